// Round 8
// baseline (114.669 us; speedup 1.0000x reference)
//
#include <hip/hip_runtime.h>
#include <hip/hip_bf16.h>

#define NSAMP 8192
#define HD 128
#define NC 18
#define SB 8            // samples per block
#define NCOLS 144       // SB*NC = 9 n-tiles of 16
#define KSTR 136        // padded k-stride in shorts (272B rows, 16B-aligned)

typedef __attribute__((ext_vector_type(8))) short bf16x8;
typedef __attribute__((ext_vector_type(4))) float f32x4;
typedef float f2 __attribute__((ext_vector_type(2)));

// Monomial map: 0:1 1:a 2:b 3:c 4:a2 5:ab 6:b2 7:ca 8:cb 9:a3 10:a2b 11:ab2
// 12:b3 13:ca2 14:cb2 15:a4 16:a2b2 17:b4   (a=dx, b=dy, c=dt)

__device__ __forceinline__ unsigned packf2(f2 v) {
    __hip_bfloat162 h = __float22bfloat162_rn(float2{v.x, v.y});
    return *(unsigned*)&h;
}
__device__ __forceinline__ f2 unpk(unsigned r) {
    f2 v;
    v.x = __uint_as_float(r << 16);
    v.y = __uint_as_float(r & 0xffff0000u);
    return v;
}

// tanh jet: out = y + s*p + P*(t2 + t3*p + t4*P), P = p^2 (18-monomial trunc)
__device__ __forceinline__ void tanh_jet2(const f2* __restrict__ f,
                                          f2* __restrict__ out) {
    f2 y;  y.x = tanhf(f[0].x);  y.y = tanhf(f[0].y);
    const f2 one = {1.0f, 1.0f};
    const f2 s  = one - y*y;
    const f2 t2 = -y*s;
    const f2 t3 = s*(y*y - 0.3333333333333333f);
    const f2 t4 = y*s*(one + one - 3.0f*y*y) * 0.3333333333333333f;
    const f2 tp1 = f[1]+f[1], tp2 = f[2]+f[2], tp3 = f[3]+f[3], tp4 = f[4]+f[4];
    f2 P[18];
    P[4]  = f[1]*f[1];
    P[5]  = tp1*f[2];
    P[6]  = f[2]*f[2];
    P[7]  = tp1*f[3];
    P[8]  = tp2*f[3];
    P[9]  = tp1*f[4];
    P[10] = tp1*f[5]  + tp2*f[4];
    P[11] = tp1*f[6]  + tp2*f[5];
    P[12] = tp2*f[6];
    P[13] = tp1*f[7]  + tp3*f[4];
    P[14] = tp2*f[8]  + tp3*f[6];
    P[15] = tp1*f[9]  + f[4]*f[4];
    P[16] = tp1*f[11] + tp2*f[10] + tp4*f[6] + f[5]*f[5];
    P[17] = tp2*f[12] + f[6]*f[6];
    f2 q[18];
    q[0] = t2;
    q[1] = t3*f[1];  q[2] = t3*f[2];  q[3] = t3*f[3];
#pragma unroll
    for (int m = 4; m <= 17; ++m) q[m] = t3*f[m] + t4*P[m];
    out[0] = y;
    out[1] = s*f[1];  out[2] = s*f[2];  out[3] = s*f[3];
    out[4] = s*f[4]  + P[4]*q[0];
    out[5] = s*f[5]  + P[5]*q[0];
    out[6] = s*f[6]  + P[6]*q[0];
    out[7] = s*f[7]  + P[7]*q[0];
    out[8] = s*f[8]  + P[8]*q[0];
    out[9]  = s*f[9]  + P[9]*q[0]  + P[4]*q[1];
    out[10] = s*f[10] + P[10]*q[0] + P[5]*q[1] + P[4]*q[2];
    out[11] = s*f[11] + P[11]*q[0] + P[6]*q[1] + P[5]*q[2];
    out[12] = s*f[12] + P[12]*q[0] + P[6]*q[2];
    out[13] = s*f[13] + P[13]*q[0] + P[7]*q[1] + P[4]*q[3];
    out[14] = s*f[14] + P[14]*q[0] + P[8]*q[2] + P[6]*q[3];
    out[15] = s*f[15] + P[15]*q[0] + P[9]*q[1] + P[4]*q[4];
    out[16] = s*f[16] + P[16]*q[0] + P[11]*q[1] + P[10]*q[2]
            + P[4]*q[6] + P[6]*q[4] + P[5]*q[5];
    out[17] = s*f[17] + P[17]*q[0] + P[12]*q[2] + P[6]*q[6];
}

// Layer-1 jet: input jet is LINEAR (p1,p2,p3 only) -> fully sparse
__device__ __forceinline__ void tanh_jet_lin2(f2 f0, f2 p1, f2 p2, f2 p3,
                                              f2* __restrict__ out) {
    f2 y;  y.x = tanhf(f0.x);  y.y = tanhf(f0.y);
    const f2 one = {1.0f, 1.0f};
    const f2 s  = one - y*y;
    const f2 t2 = -y*s;
    const f2 t3 = s*(y*y - 0.3333333333333333f);
    const f2 t4 = y*s*(one + one - 3.0f*y*y) * 0.3333333333333333f;
    const f2 tp1 = p1+p1, tp2 = p2+p2;
    const f2 P4 = p1*p1, P5 = tp1*p2, P6 = p2*p2, P7 = tp1*p3, P8 = tp2*p3;
    const f2 q0 = t2;
    const f2 q1 = t3*p1, q2 = t3*p2, q3 = t3*p3;
    const f2 q4 = t4*P4, q5 = t4*P5, q6 = t4*P6;
    out[0] = y;
    out[1] = s*p1;  out[2] = s*p2;  out[3] = s*p3;
    out[4] = P4*q0; out[5] = P5*q0; out[6] = P6*q0;
    out[7] = P7*q0; out[8] = P8*q0;
    out[9]  = P4*q1;
    out[10] = P4*q2 + P5*q1;
    out[11] = P5*q2 + P6*q1;
    out[12] = P6*q2;
    out[13] = P4*q3 + P7*q1;
    out[14] = P6*q3 + P8*q2;
    out[15] = P4*q4;
    out[16] = P4*q6 + P6*q4 + P5*q5;
    out[17] = P6*q6;
}

// ---- pre-kernel: W2,W3 fp32 [k][j] -> bf16 W^T [j][k] tight (HD) in ws ----
__global__ __launch_bounds__(256)
void transpose_w(const float* __restrict__ W2, const float* __restrict__ W3,
                 unsigned* __restrict__ wsT) {
    const int id = blockIdx.x * 256 + threadIdx.x;   // 2*128*64 = 16384 pairs
    if (id >= 2 * HD * (HD / 2)) return;
    const int L  = id / (HD * (HD / 2));
    const int r  = id % (HD * (HD / 2));
    const int j  = r / (HD / 2);
    const int kp = r % (HD / 2);
    const float* W = L ? W3 : W2;
    wsT[id] = packf2(f2{W[(2 * kp) * HD + j], W[(2 * kp + 1) * HD + j]});
}

__global__ __launch_bounds__(512, 2)
void hydro_main(const float* __restrict__ x,
                const float* __restrict__ W1, const float* __restrict__ b1,
                const float* __restrict__ b2, const float* __restrict__ b3,
                const float* __restrict__ W4, const float* __restrict__ nu_p,
                const unsigned short* __restrict__ wsT,
                float* __restrict__ out) {
    __shared__ __align__(16) unsigned short Hl[NCOLS * KSTR];  // jets/preacts, bf16
    __shared__ float psis[NCOLS];

    const int tid = threadIdx.x;
    const int wv  = tid >> 6;
    const int ln  = tid & 63;
    const int s0  = blockIdx.x * SB;

    // ---- Layer 1: 512 unit-pairs, sparse float2 jets ----
    {
        const int s  = tid >> 6;
        const int jp = tid & 63;
        const float xs = x[3 * (s0 + s) + 0];
        const float ys = x[3 * (s0 + s) + 1];
        const float ts = x[3 * (s0 + s) + 2];
        const int j0 = 2 * jp;
        const f2 wx = *(const f2*)&W1[j0];
        const f2 wy = *(const f2*)&W1[HD + j0];
        const f2 wt = *(const f2*)&W1[2 * HD + j0];
        const f2 bb = *(const f2*)&b1[j0];
        f2 h[NC];
        const f2 fc = wx * xs + wy * ys + wt * ts + bb;
        tanh_jet_lin2(fc, wx, wy, wt, h);
#pragma unroll
        for (int c = 0; c < NC; ++c)
            *(unsigned*)&Hl[(s * NC + c) * KSTR + j0] = packf2(h[c]);
    }
    __syncthreads();

    // ---- Layers 2,3: MFMA GEMM. wave = (m-group of 32 rows, n-half of 5 tiles)
    //      halves overlap at n-tile 4 (duplicate bitwise-identical writes).
    //      A-frags: one dwordx4 each from pre-transposed bf16 W^T. ----
    const int lr   = ln & 63 & 15;
    const int koff = (ln >> 4) * 8;
    const int half = wv & 1;
    const int mg   = wv >> 1;            // 0..3 -> rows 32mg..32mg+31
    const int ntb  = half * 4;           // tiles ntb..ntb+4

#pragma unroll 1
    for (int L = 0; L < 2; ++L) {
        const unsigned short* __restrict__ WT = wsT + L * HD * HD;
        bf16x8 Af[2][4];
#pragma unroll
        for (int mt = 0; mt < 2; ++mt)
#pragma unroll
            for (int ks = 0; ks < 4; ++ks)
                Af[mt][ks] = *(const bf16x8*)&WT[(mg * 32 + mt * 16 + lr) * HD + ks * 32 + koff];

        f32x4 acc[2][5];
#pragma unroll
        for (int mt = 0; mt < 2; ++mt)
#pragma unroll
            for (int t = 0; t < 5; ++t) acc[mt][t] = (f32x4)0.0f;

#pragma unroll
        for (int ks = 0; ks < 4; ++ks) {
#pragma unroll
            for (int t = 0; t < 5; ++t) {
                const bf16x8 Bf = *(const bf16x8*)&Hl[((ntb + t) * 16 + lr) * KSTR + ks * 32 + koff];
                acc[0][t] = __builtin_amdgcn_mfma_f32_16x16x32_bf16(Af[0][ks], Bf, acc[0][t], 0, 0, 0);
                acc[1][t] = __builtin_amdgcn_mfma_f32_16x16x32_bf16(Af[1][ks], Bf, acc[1][t], 0, 0, 0);
            }
        }
        __syncthreads();
        // writeback pre-activations: C[m][n] -> Hl[n][m], bf16
#pragma unroll
        for (int t = 0; t < 5; ++t) {
            const int n = (ntb + t) * 16 + lr;
#pragma unroll
            for (int mt = 0; mt < 2; ++mt) {
                const int m = mg * 32 + mt * 16 + (ln >> 4) * 4;
                uint2 w;
                w.x = packf2(f2{acc[mt][t].x, acc[mt][t].y});
                w.y = packf2(f2{acc[mt][t].z, acc[mt][t].w});
                *(uint2*)&Hl[n * KSTR + m] = w;
            }
        }
        __syncthreads();
        // tanh phase: 256 threads, unit-QUADS (b64 LDS traffic), two f2 jets each
        if (tid < 256) {
            const float* bL = L ? b3 : b2;
            const int s  = tid >> 5;
            const int q  = tid & 31;
            const int j0 = 4 * q;
            f2 fa[NC], fb[NC], ha[NC], hb[NC];
#pragma unroll
            for (int c = 0; c < NC; ++c) {
                const uint2 u = *(const uint2*)&Hl[(s * NC + c) * KSTR + j0];
                fa[c] = unpk(u.x);
                fb[c] = unpk(u.y);
            }
            fa[0] += *(const f2*)&bL[j0];
            fb[0] += *(const f2*)&bL[j0 + 2];
            tanh_jet2(fa, ha);
            tanh_jet2(fb, hb);
#pragma unroll
            for (int c = 0; c < NC; ++c) {
                uint2 w;
                w.x = packf2(ha[c]);
                w.y = packf2(hb[c]);
                *(uint2*)&Hl[(s * NC + c) * KSTR + j0] = w;
            }
        }
        __syncthreads();
    }

    // ---- Layer 4: psi jet coefs = W4 . h3 ----
    if (tid < NCOLS) {
        float acc = 0.0f;
#pragma unroll
        for (int kk = 0; kk < 16; ++kk) {
            const uint4 q = *(const uint4*)&Hl[tid * KSTR + kk * 8];
            const int k = kk * 8;
            const f2 e0 = unpk(q.x), e1 = unpk(q.y), e2 = unpk(q.z), e3 = unpk(q.w);
            acc = fmaf(e0.x, W4[k + 0], acc);
            acc = fmaf(e0.y, W4[k + 1], acc);
            acc = fmaf(e1.x, W4[k + 2], acc);
            acc = fmaf(e1.y, W4[k + 3], acc);
            acc = fmaf(e2.x, W4[k + 4], acc);
            acc = fmaf(e2.y, W4[k + 5], acc);
            acc = fmaf(e3.x, W4[k + 6], acc);
            acc = fmaf(e3.y, W4[k + 7], acc);
        }
        psis[tid] = acc;
    }
    __syncthreads();

    if (tid < SB) {
        const float* p = &psis[tid * NC];
        const float nu = nu_p[0];
        const float u  = p[2];
        const float v  = -p[1];
        const float wx = -(6.0f * p[9]  + 2.0f * p[11]);
        const float wy = -(2.0f * p[10] + 6.0f * p[12]);
        const float wt = -(2.0f * p[13] + 2.0f * p[14]);
        const float lapw = -(24.0f * p[15] + 8.0f * p[16] + 24.0f * p[17]);
        const float nse  = wt + wx * u + wy * v - nu * lapw;
        const int gi = s0 + tid;
        out[2 * gi]         = u;
        out[2 * gi + 1]     = v;
        out[2 * NSAMP + gi] = nse;
    }
}

extern "C" void kernel_launch(void* const* d_in, const int* in_sizes, int n_in,
                              void* d_out, int out_size, void* d_ws, size_t ws_size,
                              hipStream_t stream) {
    const float* x  = (const float*)d_in[0];
    const float* W1 = (const float*)d_in[1];
    const float* b1 = (const float*)d_in[2];
    const float* W2 = (const float*)d_in[3];
    const float* b2 = (const float*)d_in[4];
    const float* W3 = (const float*)d_in[5];
    const float* b3 = (const float*)d_in[6];
    const float* W4 = (const float*)d_in[7];
    const float* nu = (const float*)d_in[9];
    float* out = (float*)d_out;

    unsigned* wsT = (unsigned*)d_ws;   // 2 x 128 x 128 bf16 = 65536 B
    hipLaunchKernelGGL(transpose_w, dim3(64), dim3(256), 0, stream, W2, W3, wsT);
    hipLaunchKernelGGL(hydro_main, dim3(NSAMP / SB), dim3(512), 0, stream,
                       x, W1, b1, b2, b3, W4, nu,
                       (const unsigned short*)d_ws, out);
}

// Round 9
// 105.319 us; speedup vs baseline: 1.0888x; 1.0888x over previous
//
#include <hip/hip_runtime.h>
#include <hip/hip_bf16.h>

#define NSAMP 8192
#define HD 128
#define NC 18
#define SB 8            // samples per block
#define NCOLS 144       // SB*NC = 9 n-tiles of 16
#define KSTR 136        // padded k-stride in shorts (272B rows, 16B-aligned)

typedef __attribute__((ext_vector_type(8))) short bf16x8;
typedef __attribute__((ext_vector_type(4))) float f32x4;
typedef float f2 __attribute__((ext_vector_type(2)));

// Monomial map: 0:1 1:a 2:b 3:c 4:a2 5:ab 6:b2 7:ca 8:cb 9:a3 10:a2b 11:ab2
// 12:b3 13:ca2 14:cb2 15:a4 16:a2b2 17:b4   (a=dx, b=dy, c=dt)

__device__ __forceinline__ unsigned packf2(f2 v) {
    __hip_bfloat162 h = __float22bfloat162_rn(float2{v.x, v.y});
    return *(unsigned*)&h;
}
__device__ __forceinline__ f2 unpk(unsigned r) {
    f2 v;
    v.x = __uint_as_float(r << 16);
    v.y = __uint_as_float(r & 0xffff0000u);
    return v;
}

// tanh jet: out = y + s*p + P*(t2 + t3*p + t4*P), P = p^2 (18-monomial trunc)
__device__ __forceinline__ void tanh_jet2(const f2* __restrict__ f,
                                          f2* __restrict__ out) {
    f2 y;  y.x = tanhf(f[0].x);  y.y = tanhf(f[0].y);
    const f2 one = {1.0f, 1.0f};
    const f2 s  = one - y*y;
    const f2 t2 = -y*s;
    const f2 t3 = s*(y*y - 0.3333333333333333f);
    const f2 t4 = y*s*(one + one - 3.0f*y*y) * 0.3333333333333333f;
    const f2 tp1 = f[1]+f[1], tp2 = f[2]+f[2], tp3 = f[3]+f[3], tp4 = f[4]+f[4];
    f2 P[18];
    P[4]  = f[1]*f[1];
    P[5]  = tp1*f[2];
    P[6]  = f[2]*f[2];
    P[7]  = tp1*f[3];
    P[8]  = tp2*f[3];
    P[9]  = tp1*f[4];
    P[10] = tp1*f[5]  + tp2*f[4];
    P[11] = tp1*f[6]  + tp2*f[5];
    P[12] = tp2*f[6];
    P[13] = tp1*f[7]  + tp3*f[4];
    P[14] = tp2*f[8]  + tp3*f[6];
    P[15] = tp1*f[9]  + f[4]*f[4];
    P[16] = tp1*f[11] + tp2*f[10] + tp4*f[6] + f[5]*f[5];
    P[17] = tp2*f[12] + f[6]*f[6];
    f2 q[18];
    q[0] = t2;
    q[1] = t3*f[1];  q[2] = t3*f[2];  q[3] = t3*f[3];
#pragma unroll
    for (int m = 4; m <= 17; ++m) q[m] = t3*f[m] + t4*P[m];
    out[0] = y;
    out[1] = s*f[1];  out[2] = s*f[2];  out[3] = s*f[3];
    out[4] = s*f[4]  + P[4]*q[0];
    out[5] = s*f[5]  + P[5]*q[0];
    out[6] = s*f[6]  + P[6]*q[0];
    out[7] = s*f[7]  + P[7]*q[0];
    out[8] = s*f[8]  + P[8]*q[0];
    out[9]  = s*f[9]  + P[9]*q[0]  + P[4]*q[1];
    out[10] = s*f[10] + P[10]*q[0] + P[5]*q[1] + P[4]*q[2];
    out[11] = s*f[11] + P[11]*q[0] + P[6]*q[1] + P[5]*q[2];
    out[12] = s*f[12] + P[12]*q[0] + P[6]*q[2];
    out[13] = s*f[13] + P[13]*q[0] + P[7]*q[1] + P[4]*q[3];
    out[14] = s*f[14] + P[14]*q[0] + P[8]*q[2] + P[6]*q[3];
    out[15] = s*f[15] + P[15]*q[0] + P[9]*q[1] + P[4]*q[4];
    out[16] = s*f[16] + P[16]*q[0] + P[11]*q[1] + P[10]*q[2]
            + P[4]*q[6] + P[6]*q[4] + P[5]*q[5];
    out[17] = s*f[17] + P[17]*q[0] + P[12]*q[2] + P[6]*q[6];
}

// Layer-1 jet: input jet is LINEAR (p1,p2,p3 only) -> fully sparse
__device__ __forceinline__ void tanh_jet_lin2(f2 f0, f2 p1, f2 p2, f2 p3,
                                              f2* __restrict__ out) {
    f2 y;  y.x = tanhf(f0.x);  y.y = tanhf(f0.y);
    const f2 one = {1.0f, 1.0f};
    const f2 s  = one - y*y;
    const f2 t2 = -y*s;
    const f2 t3 = s*(y*y - 0.3333333333333333f);
    const f2 t4 = y*s*(one + one - 3.0f*y*y) * 0.3333333333333333f;
    const f2 tp1 = p1+p1, tp2 = p2+p2;
    const f2 P4 = p1*p1, P5 = tp1*p2, P6 = p2*p2, P7 = tp1*p3, P8 = tp2*p3;
    const f2 q0 = t2;
    const f2 q1 = t3*p1, q2 = t3*p2, q3 = t3*p3;
    const f2 q4 = t4*P4, q5 = t4*P5, q6 = t4*P6;
    out[0] = y;
    out[1] = s*p1;  out[2] = s*p2;  out[3] = s*p3;
    out[4] = P4*q0; out[5] = P5*q0; out[6] = P6*q0;
    out[7] = P7*q0; out[8] = P8*q0;
    out[9]  = P4*q1;
    out[10] = P4*q2 + P5*q1;
    out[11] = P5*q2 + P6*q1;
    out[12] = P6*q2;
    out[13] = P4*q3 + P7*q1;
    out[14] = P6*q3 + P8*q2;
    out[15] = P4*q4;
    out[16] = P4*q6 + P6*q4 + P5*q5;
    out[17] = P6*q6;
}

// ---- pre-kernel: W2,W3 fp32 [k][j] -> bf16 W^T [j][k] tight (HD) in ws ----
__global__ __launch_bounds__(256)
void transpose_w(const float* __restrict__ W2, const float* __restrict__ W3,
                 unsigned* __restrict__ wsT) {
    const int id = blockIdx.x * 256 + threadIdx.x;   // 2*128*64 = 16384 pairs
    if (id >= 2 * HD * (HD / 2)) return;
    const int L  = id / (HD * (HD / 2));
    const int r  = id % (HD * (HD / 2));
    const int j  = r / (HD / 2);
    const int kp = r % (HD / 2);
    const float* W = L ? W3 : W2;
    wsT[id] = packf2(f2{W[(2 * kp) * HD + j], W[(2 * kp + 1) * HD + j]});
}

// NOTE: __launch_bounds__ second arg empirically acts as a residency CAP on
// this ROCm: (512,2) rounds (R6,R8) ran at occ ~19-22% (1 block/CU, serial
// rounds); (512,4) rounds (R4,R5,R7) at 30-36%. Keep 4.
__global__ __launch_bounds__(512, 4)
void hydro_main(const float* __restrict__ x,
                const float* __restrict__ W1, const float* __restrict__ b1,
                const float* __restrict__ b2, const float* __restrict__ b3,
                const float* __restrict__ W4, const float* __restrict__ nu_p,
                const unsigned short* __restrict__ wsT,
                float* __restrict__ out) {
    __shared__ __align__(16) unsigned short Hl[NCOLS * KSTR];  // jets/preacts, bf16
    __shared__ float psis[NCOLS];

    const int tid = threadIdx.x;
    const int wv  = tid >> 6;
    const int ln  = tid & 63;
    const int s0  = blockIdx.x * SB;

    // ---- Layer 1: 512 unit-pairs, sparse float2 jets ----
    {
        const int s  = tid >> 6;
        const int jp = tid & 63;
        const float xs = x[3 * (s0 + s) + 0];
        const float ys = x[3 * (s0 + s) + 1];
        const float ts = x[3 * (s0 + s) + 2];
        const int j0 = 2 * jp;
        const f2 wx = *(const f2*)&W1[j0];
        const f2 wy = *(const f2*)&W1[HD + j0];
        const f2 wt = *(const f2*)&W1[2 * HD + j0];
        const f2 bb = *(const f2*)&b1[j0];
        f2 h[NC];
        const f2 fc = wx * xs + wy * ys + wt * ts + bb;
        tanh_jet_lin2(fc, wx, wy, wt, h);
#pragma unroll
        for (int c = 0; c < NC; ++c)
            *(unsigned*)&Hl[(s * NC + c) * KSTR + j0] = packf2(h[c]);
    }
    __syncthreads();

    // ---- Layers 2,3: MFMA GEMM. wave = (m-group of 32 rows, n-half of 5 tiles)
    //      halves overlap at n-tile 4 (duplicate bitwise-identical writes).
    //      A-frags: one dwordx4 each from pre-transposed bf16 W^T. ----
    const int lr   = ln & 15;
    const int koff = (ln >> 4) * 8;
    const int half = wv & 1;
    const int mg   = wv >> 1;            // 0..3 -> rows 32mg..32mg+31
    const int ntb  = half * 4;           // tiles ntb..ntb+4

#pragma unroll 1
    for (int L = 0; L < 2; ++L) {
        const unsigned short* __restrict__ WT = wsT + L * HD * HD;
        bf16x8 Af[2][4];
#pragma unroll
        for (int mt = 0; mt < 2; ++mt)
#pragma unroll
            for (int ks = 0; ks < 4; ++ks)
                Af[mt][ks] = *(const bf16x8*)&WT[(mg * 32 + mt * 16 + lr) * HD + ks * 32 + koff];

        f32x4 acc[2][5];
#pragma unroll
        for (int mt = 0; mt < 2; ++mt)
#pragma unroll
            for (int t = 0; t < 5; ++t) acc[mt][t] = (f32x4)0.0f;

#pragma unroll
        for (int ks = 0; ks < 4; ++ks) {
#pragma unroll
            for (int t = 0; t < 5; ++t) {
                const bf16x8 Bf = *(const bf16x8*)&Hl[((ntb + t) * 16 + lr) * KSTR + ks * 32 + koff];
                acc[0][t] = __builtin_amdgcn_mfma_f32_16x16x32_bf16(Af[0][ks], Bf, acc[0][t], 0, 0, 0);
                acc[1][t] = __builtin_amdgcn_mfma_f32_16x16x32_bf16(Af[1][ks], Bf, acc[1][t], 0, 0, 0);
            }
        }
        __syncthreads();
        // writeback pre-activations: C[m][n] -> Hl[n][m], bf16
#pragma unroll
        for (int t = 0; t < 5; ++t) {
            const int n = (ntb + t) * 16 + lr;
#pragma unroll
            for (int mt = 0; mt < 2; ++mt) {
                const int m = mg * 32 + mt * 16 + (ln >> 4) * 4;
                uint2 w;
                w.x = packf2(f2{acc[mt][t].x, acc[mt][t].y});
                w.y = packf2(f2{acc[mt][t].z, acc[mt][t].w});
                *(uint2*)&Hl[n * KSTR + m] = w;
            }
        }
        __syncthreads();
        // tanh phase: 256 threads, unit-QUADS (b64 LDS traffic), two f2 jets each
        if (tid < 256) {
            const float* bL = L ? b3 : b2;
            const int s  = tid >> 5;
            const int q  = tid & 31;
            const int j0 = 4 * q;
            f2 fa[NC], fb[NC], ha[NC], hb[NC];
#pragma unroll
            for (int c = 0; c < NC; ++c) {
                const uint2 u = *(const uint2*)&Hl[(s * NC + c) * KSTR + j0];
                fa[c] = unpk(u.x);
                fb[c] = unpk(u.y);
            }
            fa[0] += *(const f2*)&bL[j0];
            fb[0] += *(const f2*)&bL[j0 + 2];
            tanh_jet2(fa, ha);
            tanh_jet2(fb, hb);
#pragma unroll
            for (int c = 0; c < NC; ++c) {
                uint2 w;
                w.x = packf2(ha[c]);
                w.y = packf2(hb[c]);
                *(uint2*)&Hl[(s * NC + c) * KSTR + j0] = w;
            }
        }
        __syncthreads();
    }

    // ---- Layer 4: psi jet coefs = W4 . h3 ----
    if (tid < NCOLS) {
        float acc = 0.0f;
#pragma unroll
        for (int kk = 0; kk < 16; ++kk) {
            const uint4 q = *(const uint4*)&Hl[tid * KSTR + kk * 8];
            const int k = kk * 8;
            const f2 e0 = unpk(q.x), e1 = unpk(q.y), e2 = unpk(q.z), e3 = unpk(q.w);
            acc = fmaf(e0.x, W4[k + 0], acc);
            acc = fmaf(e0.y, W4[k + 1], acc);
            acc = fmaf(e1.x, W4[k + 2], acc);
            acc = fmaf(e1.y, W4[k + 3], acc);
            acc = fmaf(e2.x, W4[k + 4], acc);
            acc = fmaf(e2.y, W4[k + 5], acc);
            acc = fmaf(e3.x, W4[k + 6], acc);
            acc = fmaf(e3.y, W4[k + 7], acc);
        }
        psis[tid] = acc;
    }
    __syncthreads();

    if (tid < SB) {
        const float* p = &psis[tid * NC];
        const float nu = nu_p[0];
        const float u  = p[2];
        const float v  = -p[1];
        const float wx = -(6.0f * p[9]  + 2.0f * p[11]);
        const float wy = -(2.0f * p[10] + 6.0f * p[12]);
        const float wt = -(2.0f * p[13] + 2.0f * p[14]);
        const float lapw = -(24.0f * p[15] + 8.0f * p[16] + 24.0f * p[17]);
        const float nse  = wt + wx * u + wy * v - nu * lapw;
        const int gi = s0 + tid;
        out[2 * gi]         = u;
        out[2 * gi + 1]     = v;
        out[2 * NSAMP + gi] = nse;
    }
}

extern "C" void kernel_launch(void* const* d_in, const int* in_sizes, int n_in,
                              void* d_out, int out_size, void* d_ws, size_t ws_size,
                              hipStream_t stream) {
    const float* x  = (const float*)d_in[0];
    const float* W1 = (const float*)d_in[1];
    const float* b1 = (const float*)d_in[2];
    const float* W2 = (const float*)d_in[3];
    const float* b2 = (const float*)d_in[4];
    const float* W3 = (const float*)d_in[5];
    const float* b3 = (const float*)d_in[6];
    const float* W4 = (const float*)d_in[7];
    const float* nu = (const float*)d_in[9];
    float* out = (float*)d_out;

    unsigned* wsT = (unsigned*)d_ws;   // 2 x 128 x 128 bf16 = 65536 B
    hipLaunchKernelGGL(transpose_w, dim3(64), dim3(256), 0, stream, W2, W3, wsT);
    hipLaunchKernelGGL(hydro_main, dim3(NSAMP / SB), dim3(512), 0, stream,
                       x, W1, b1, b2, b3, W4, nu,
                       (const unsigned short*)d_ws, out);
}

// Round 10
// 95.684 us; speedup vs baseline: 1.1984x; 1.1007x over previous
//
#include <hip/hip_runtime.h>
#include <hip/hip_bf16.h>

#define NSAMP 8192
#define HD 128
#define NC 18
#define SB 8            // samples per block
#define NCOLS 144       // SB*NC = 9 n-tiles of 16
#define KSTR 136        // padded k-stride in shorts (272B rows, 16B-aligned)

typedef __attribute__((ext_vector_type(8))) short bf16x8;
typedef __attribute__((ext_vector_type(4))) float f32x4;
typedef float f2 __attribute__((ext_vector_type(2)));

// Monomial map: 0:1 1:a 2:b 3:c 4:a2 5:ab 6:b2 7:ca 8:cb 9:a3 10:a2b 11:ab2
// 12:b3 13:ca2 14:cb2 15:a4 16:a2b2 17:b4   (a=dx, b=dy, c=dt)

__device__ __forceinline__ unsigned packf2(f2 v) {
    __hip_bfloat162 h = __float22bfloat162_rn(float2{v.x, v.y});
    return *(unsigned*)&h;
}
__device__ __forceinline__ f2 unpk(unsigned r) {
    f2 v;
    v.x = __uint_as_float(r << 16);
    v.y = __uint_as_float(r & 0xffff0000u);
    return v;
}

// tanh jet: out = y + s*p + P*(t2 + t3*p + t4*P), P = p^2 (18-monomial trunc)
__device__ __forceinline__ void tanh_jet2(const f2* __restrict__ f,
                                          f2* __restrict__ out) {
    f2 y;  y.x = tanhf(f[0].x);  y.y = tanhf(f[0].y);
    const f2 one = {1.0f, 1.0f};
    const f2 s  = one - y*y;
    const f2 t2 = -y*s;
    const f2 t3 = s*(y*y - 0.3333333333333333f);
    const f2 t4 = y*s*(one + one - 3.0f*y*y) * 0.3333333333333333f;
    const f2 tp1 = f[1]+f[1], tp2 = f[2]+f[2], tp3 = f[3]+f[3], tp4 = f[4]+f[4];
    f2 P[18];
    P[4]  = f[1]*f[1];
    P[5]  = tp1*f[2];
    P[6]  = f[2]*f[2];
    P[7]  = tp1*f[3];
    P[8]  = tp2*f[3];
    P[9]  = tp1*f[4];
    P[10] = tp1*f[5]  + tp2*f[4];
    P[11] = tp1*f[6]  + tp2*f[5];
    P[12] = tp2*f[6];
    P[13] = tp1*f[7]  + tp3*f[4];
    P[14] = tp2*f[8]  + tp3*f[6];
    P[15] = tp1*f[9]  + f[4]*f[4];
    P[16] = tp1*f[11] + tp2*f[10] + tp4*f[6] + f[5]*f[5];
    P[17] = tp2*f[12] + f[6]*f[6];
    f2 q[18];
    q[0] = t2;
    q[1] = t3*f[1];  q[2] = t3*f[2];  q[3] = t3*f[3];
#pragma unroll
    for (int m = 4; m <= 17; ++m) q[m] = t3*f[m] + t4*P[m];
    out[0] = y;
    out[1] = s*f[1];  out[2] = s*f[2];  out[3] = s*f[3];
    out[4] = s*f[4]  + P[4]*q[0];
    out[5] = s*f[5]  + P[5]*q[0];
    out[6] = s*f[6]  + P[6]*q[0];
    out[7] = s*f[7]  + P[7]*q[0];
    out[8] = s*f[8]  + P[8]*q[0];
    out[9]  = s*f[9]  + P[9]*q[0]  + P[4]*q[1];
    out[10] = s*f[10] + P[10]*q[0] + P[5]*q[1] + P[4]*q[2];
    out[11] = s*f[11] + P[11]*q[0] + P[6]*q[1] + P[5]*q[2];
    out[12] = s*f[12] + P[12]*q[0] + P[6]*q[2];
    out[13] = s*f[13] + P[13]*q[0] + P[7]*q[1] + P[4]*q[3];
    out[14] = s*f[14] + P[14]*q[0] + P[8]*q[2] + P[6]*q[3];
    out[15] = s*f[15] + P[15]*q[0] + P[9]*q[1] + P[4]*q[4];
    out[16] = s*f[16] + P[16]*q[0] + P[11]*q[1] + P[10]*q[2]
            + P[4]*q[6] + P[6]*q[4] + P[5]*q[5];
    out[17] = s*f[17] + P[17]*q[0] + P[12]*q[2] + P[6]*q[6];
}

// Layer-1 jet: input jet is LINEAR (p1,p2,p3 only) -> fully sparse
__device__ __forceinline__ void tanh_jet_lin2(f2 f0, f2 p1, f2 p2, f2 p3,
                                              f2* __restrict__ out) {
    f2 y;  y.x = tanhf(f0.x);  y.y = tanhf(f0.y);
    const f2 one = {1.0f, 1.0f};
    const f2 s  = one - y*y;
    const f2 t2 = -y*s;
    const f2 t3 = s*(y*y - 0.3333333333333333f);
    const f2 t4 = y*s*(one + one - 3.0f*y*y) * 0.3333333333333333f;
    const f2 tp1 = p1+p1, tp2 = p2+p2;
    const f2 P4 = p1*p1, P5 = tp1*p2, P6 = p2*p2, P7 = tp1*p3, P8 = tp2*p3;
    const f2 q0 = t2;
    const f2 q1 = t3*p1, q2 = t3*p2, q3 = t3*p3;
    const f2 q4 = t4*P4, q5 = t4*P5, q6 = t4*P6;
    out[0] = y;
    out[1] = s*p1;  out[2] = s*p2;  out[3] = s*p3;
    out[4] = P4*q0; out[5] = P5*q0; out[6] = P6*q0;
    out[7] = P7*q0; out[8] = P8*q0;
    out[9]  = P4*q1;
    out[10] = P4*q2 + P5*q1;
    out[11] = P5*q2 + P6*q1;
    out[12] = P6*q2;
    out[13] = P4*q3 + P7*q1;
    out[14] = P6*q3 + P8*q2;
    out[15] = P4*q4;
    out[16] = P4*q6 + P6*q4 + P5*q5;
    out[17] = P6*q6;
}

// ---- pre-kernel: W2,W3 fp32 [k][j] -> bf16 W^T [j][k] tight (HD) in ws ----
__global__ __launch_bounds__(256)
void transpose_w(const float* __restrict__ W2, const float* __restrict__ W3,
                 unsigned* __restrict__ wsT) {
    const int id = blockIdx.x * 256 + threadIdx.x;   // 2*128*64 = 16384 pairs
    if (id >= 2 * HD * (HD / 2)) return;
    const int L  = id / (HD * (HD / 2));
    const int r  = id % (HD * (HD / 2));
    const int j  = r / (HD / 2);
    const int kp = r % (HD / 2);
    const float* W = L ? W3 : W2;
    wsT[id] = packf2(f2{W[(2 * kp) * HD + j], W[(2 * kp + 1) * HD + j]});
}

// NOTES (measured across R4-R9):
// - __launch_bounds__ 2nd arg acts as a residency cap: (512,2) -> ~20% occ
//   (R6,R8 regressions); keep (512,4).
// - VGPR=64 is load-bearing: 8 waves/SIMD x 4 blocks/CU needs <=64. Do not
//   add register-hungry prefetch.
// - GEMM tiling wave=(1 m-tile x 9 n-tiles) beats 2x5 m-grouping by ~13us
//   (R5/R9 both regressed; bank conflicts 10x higher there).
__global__ __launch_bounds__(512, 4)
void hydro_main(const float* __restrict__ x,
                const float* __restrict__ W1, const float* __restrict__ b1,
                const float* __restrict__ b2, const float* __restrict__ b3,
                const float* __restrict__ W4, const float* __restrict__ nu_p,
                const unsigned short* __restrict__ wsT,
                float* __restrict__ out) {
    __shared__ __align__(16) unsigned short Hl[NCOLS * KSTR];  // jets/preacts, bf16
    __shared__ float psis[NCOLS];

    const int tid = threadIdx.x;
    const int wv  = tid >> 6;
    const int ln  = tid & 63;
    const int s0  = blockIdx.x * SB;
    const int s   = tid >> 6;          // sample slot 0..7
    const int jp  = tid & 63;          // unit pair 0..63

    // ---- Layer 1: 512 unit-pairs, sparse float2 jets ----
    {
        const float xs = x[3 * (s0 + s) + 0];
        const float ys = x[3 * (s0 + s) + 1];
        const float ts = x[3 * (s0 + s) + 2];
        const int j0 = 2 * jp;
        const f2 wx = *(const f2*)&W1[j0];
        const f2 wy = *(const f2*)&W1[HD + j0];
        const f2 wt = *(const f2*)&W1[2 * HD + j0];
        const f2 bb = *(const f2*)&b1[j0];
        f2 h[NC];
        const f2 fc = wx * xs + wy * ys + wt * ts + bb;
        tanh_jet_lin2(fc, wx, wy, wt, h);
#pragma unroll
        for (int c = 0; c < NC; ++c)
            *(unsigned*)&Hl[(s * NC + c) * KSTR + j0] = packf2(h[c]);
    }
    __syncthreads();

    // ---- Layers 2,3: MFMA GEMM (A from pre-transposed W^T) + tanh ----
    const int lr   = ln & 15;
    const int koff = (ln >> 4) * 8;

#pragma unroll 1
    for (int L = 0; L < 2; ++L) {
        const unsigned short* __restrict__ WT = wsT + L * HD * HD;
        // A-frags for m-tile wv: 4 x global_load_dwordx4, L1/L2-hot
        bf16x8 Af[4];
#pragma unroll
        for (int ks = 0; ks < 4; ++ks)
            Af[ks] = *(const bf16x8*)&WT[(wv * 16 + lr) * HD + ks * 32 + koff];
        f32x4 acc[9];
#pragma unroll
        for (int nt = 0; nt < 9; ++nt) acc[nt] = (f32x4)0.0f;
#pragma unroll
        for (int ks = 0; ks < 4; ++ks) {
#pragma unroll
            for (int nt = 0; nt < 9; ++nt) {
                const bf16x8 Bf = *(const bf16x8*)&Hl[(nt * 16 + lr) * KSTR + ks * 32 + koff];
                acc[nt] = __builtin_amdgcn_mfma_f32_16x16x32_bf16(Af[ks], Bf, acc[nt], 0, 0, 0);
            }
        }
        __syncthreads();
        // writeback pre-activations: C[m][n] -> Hl[n][m], bf16
#pragma unroll
        for (int nt = 0; nt < 9; ++nt) {
            const int n = nt * 16 + lr;
            const int m = wv * 16 + (ln >> 4) * 4;
            uint2 w;
            w.x = packf2(f2{acc[nt].x, acc[nt].y});
            w.y = packf2(f2{acc[nt].z, acc[nt].w});
            *(uint2*)&Hl[n * KSTR + m] = w;
        }
        __syncthreads();
        // tanh phase: ALL 512 threads, one f2-jet each, b32 LDS ops
        // (wave-uniform row + lane-contiguous dwords -> conflict-free)
        {
            const float* bL = L ? b3 : b2;
            const int j0 = 2 * jp;
            f2 fa[NC], ha[NC];
#pragma unroll
            for (int c = 0; c < NC; ++c)
                fa[c] = unpk(*(const unsigned*)&Hl[(s * NC + c) * KSTR + j0]);
            fa[0] += *(const f2*)&bL[j0];
            tanh_jet2(fa, ha);
#pragma unroll
            for (int c = 0; c < NC; ++c)
                *(unsigned*)&Hl[(s * NC + c) * KSTR + j0] = packf2(ha[c]);
        }
        __syncthreads();
    }

    // ---- Layer 4: psi jet coefs = W4 . h3 ----
    if (tid < NCOLS) {
        float acc = 0.0f;
#pragma unroll
        for (int kk = 0; kk < 16; ++kk) {
            const uint4 q = *(const uint4*)&Hl[tid * KSTR + kk * 8];
            const int k = kk * 8;
            const f2 e0 = unpk(q.x), e1 = unpk(q.y), e2 = unpk(q.z), e3 = unpk(q.w);
            acc = fmaf(e0.x, W4[k + 0], acc);
            acc = fmaf(e0.y, W4[k + 1], acc);
            acc = fmaf(e1.x, W4[k + 2], acc);
            acc = fmaf(e1.y, W4[k + 3], acc);
            acc = fmaf(e2.x, W4[k + 4], acc);
            acc = fmaf(e2.y, W4[k + 5], acc);
            acc = fmaf(e3.x, W4[k + 6], acc);
            acc = fmaf(e3.y, W4[k + 7], acc);
        }
        psis[tid] = acc;
    }
    __syncthreads();

    if (tid < SB) {
        const float* p = &psis[tid * NC];
        const float nu = nu_p[0];
        const float u  = p[2];
        const float v  = -p[1];
        const float wx = -(6.0f * p[9]  + 2.0f * p[11]);
        const float wy = -(2.0f * p[10] + 6.0f * p[12]);
        const float wt = -(2.0f * p[13] + 2.0f * p[14]);
        const float lapw = -(24.0f * p[15] + 8.0f * p[16] + 24.0f * p[17]);
        const float nse  = wt + wx * u + wy * v - nu * lapw;
        const int gi = s0 + tid;
        out[2 * gi]         = u;
        out[2 * gi + 1]     = v;
        out[2 * NSAMP + gi] = nse;
    }
}

extern "C" void kernel_launch(void* const* d_in, const int* in_sizes, int n_in,
                              void* d_out, int out_size, void* d_ws, size_t ws_size,
                              hipStream_t stream) {
    const float* x  = (const float*)d_in[0];
    const float* W1 = (const float*)d_in[1];
    const float* b1 = (const float*)d_in[2];
    const float* W2 = (const float*)d_in[3];
    const float* b2 = (const float*)d_in[4];
    const float* W3 = (const float*)d_in[5];
    const float* b3 = (const float*)d_in[6];
    const float* W4 = (const float*)d_in[7];
    const float* nu = (const float*)d_in[9];
    float* out = (float*)d_out;

    unsigned* wsT = (unsigned*)d_ws;   // 2 x 128 x 128 bf16 = 65536 B
    hipLaunchKernelGGL(transpose_w, dim3(64), dim3(256), 0, stream, W2, W3, wsT);
    hipLaunchKernelGGL(hydro_main, dim3(NSAMP / SB), dim3(512), 0, stream,
                       x, W1, b1, b2, b3, W4, nu,
                       (const unsigned short*)d_ws, out);
}